// Round 1
// 220.557 us; speedup vs baseline: 1.1042x; 1.1042x over previous
//
#include <hip/hip_runtime.h>
#include <math.h>

#define T_LEN 100
#define K_LEN 25
#define DLAT 64
#define DHID 128
#define CST 68

// ---------------------------------------------------------------------------
// buildW: collapse Conv1d(1,64,25,pad=12) + Linear(100,1) into one matrix:
//   h2[n,c] = sum_i x[n,i] * W[c,i] + b2[c]
// ---------------------------------------------------------------------------
__global__ __launch_bounds__(256) void buildW(const float* __restrict__ conv_w,
                                              const float* __restrict__ conv_b,
                                              const float* __restrict__ fc1_w,
                                              const float* __restrict__ fc1_b,
                                              float* __restrict__ W,
                                              float* __restrict__ b2) {
    int idx = blockIdx.x * 256 + threadIdx.x;
    if (idx < 64 * T_LEN) {
        int c = idx / T_LEN, i = idx % T_LEN;
        int t0 = i - 12 > 0 ? i - 12 : 0;
        int t1 = i + 12 < T_LEN - 1 ? i + 12 : T_LEN - 1;
        float acc = 0.f;
        for (int t = t0; t <= t1; ++t)
            acc += fc1_w[t] * conv_w[c * K_LEN + (i - t + 12)];
        W[idx] = acc;
    } else if (idx < 64 * T_LEN + 64) {
        int c = idx - 64 * T_LEN;
        float S = 0.f;
        for (int t = 0; t < T_LEN; ++t) S += fc1_w[t];
        b2[c] = conv_b[c] * S + fc1_b[0];
    }
}

// ---------------------------------------------------------------------------
// Phase A: h2 = x @ W^T + b2.  512 thr = 8 waves; wave w owns channels
// [8w, 8w+8); lane = node.  W reads are wave-uniform -> scalar path.
// 8 waves/block, grid 512 -> 2 blocks/CU -> 16 waves/CU (VGPR ~24).
// ---------------------------------------------------------------------------
__global__ __launch_bounds__(512) void phaseA3(const float* __restrict__ x,
                                               const float* __restrict__ W,
                                               const float* __restrict__ b2,
                                               float* __restrict__ h2) {
    int lane = threadIdx.x & 63;
    int w = __builtin_amdgcn_readfirstlane((int)(threadIdx.x >> 6));  // 0..7
    int node = blockIdx.x * 64 + lane;
    const float* __restrict__ Wb = W + w * 8 * T_LEN;  // uniform base
    const float4* __restrict__ xp = (const float4*)(x + (size_t)node * T_LEN);

    float acc[8];
#pragma unroll
    for (int c = 0; c < 8; ++c) acc[c] = 0.f;

#pragma unroll
    for (int tq = 0; tq < T_LEN / 4; ++tq) {
        float4 xv = xp[tq];
#pragma unroll
        for (int c = 0; c < 8; ++c) {
            const float* wr = Wb + c * T_LEN + tq * 4;  // uniform -> s_load
            acc[c] += xv.x * wr[0] + xv.y * wr[1] + xv.z * wr[2] + xv.w * wr[3];
        }
    }

    float* __restrict__ out = h2 + (size_t)node * DLAT + w * 8;
#pragma unroll
    for (int q = 0; q < 2; ++q) {
        float4 o;
        o.x = acc[4 * q + 0] + b2[w * 8 + 4 * q + 0];
        o.y = acc[4 * q + 1] + b2[w * 8 + 4 * q + 1];
        o.z = acc[4 * q + 2] + b2[w * 8 + 4 * q + 2];
        o.w = acc[4 * q + 3] + b2[w * 8 + 4 * q + 3];
        *(float4*)(out + 4 * q) = o;
    }
}

// ---------------------------------------------------------------------------
// Phase C (fused): per graph g, one 512-thread block (8 waves):
//   1. count this graph's 2048 edges into a 64x64 LDS tile via ds atomics
//      (replaces global phaseB + memset + 24 MB adjacency traffic)
//   2. agg = A @ h2_block  (64x64x64)
//   3. out[n,j] = agg[n,:]·rel_w[j,:] + h2[n,:]·root_w[j,:] + rel_b[j]
//      j-innermost: acc[16] per lane, weights on the scalar path, agg/h2
//      rows read from LDS ONCE per m-step (32 b128/lane total, not per-j)
//   emit Sg[g,j]=sum_n out, Qg[g,j]=sum_n out^2
// XCD-bijective graph swizzle: the 16 graphs sharing each edge cacheline
// land on the same XCD -> edge refetches are L2 hits.
// 8 waves * grid 512 -> 16 waves/CU; LDS 50.25 KB -> 2 blocks/CU fit.
// ---------------------------------------------------------------------------
__global__ __launch_bounds__(512, 4) void phaseCF(const float* __restrict__ h2,
                                                  const int* __restrict__ ei,
                                                  const float* __restrict__ rel_w,
                                                  const float* __restrict__ rel_b,
                                                  const float* __restrict__ root_w,
                                                  float* __restrict__ Sg,
                                                  float* __restrict__ Qg,
                                                  int E, int G) {
    __shared__ float h2s[64 * CST];
    __shared__ float aggs[64 * CST];
    __shared__ unsigned Asu[64 * 65];
    float* Asf = (float*)Asu;

    int tid = threadIdx.x;
    int bid = blockIdx.x;

    // bijective XCD swizzle (m204): XCD k gets a contiguous graph chunk
    int q = G >> 3, r = G & 7;
    int xc = bid & 7, o = bid >> 3;
    int g = (xc < r ? xc * (q + 1) : r * (q + 1) + (xc - r) * q) + o;

    int epg = E / G;  // 2048 for the target shape

    // issue the strided edge loads EARLY so they overlap the LDS staging
    int es0 = 0, es1 = 0, es2 = 0, es3 = 0;
    int ed0 = 0, ed1 = 0, ed2 = 0, ed3 = 0;
    bool fast = (epg == 2048);
    if (fast) {
        int e0 = g + tid * G;   // edge e belongs to graph e % G
        int st = 512 * G;
        es0 = ei[e0];            ed0 = ei[E + e0];
        es1 = ei[e0 + st];       ed1 = ei[E + e0 + st];
        es2 = ei[e0 + 2 * st];   ed2 = ei[E + e0 + 2 * st];
        es3 = ei[e0 + 3 * st];   ed3 = ei[E + e0 + 3 * st];
    }

    // zero adjacency + stage h2 tile
    for (int idx = tid; idx < 64 * 65; idx += 512) Asu[idx] = 0u;
    const float* __restrict__ hsrc = h2 + (size_t)g * 64 * DLAT;
    for (int idx = tid; idx < 4096; idx += 512)
        h2s[(idx >> 6) * CST + (idx & 63)] = hsrc[idx];
    __syncthreads();

    if (fast) {
        atomicAdd(&Asu[(ed0 & 63) * 65 + (es0 & 63)], 1u);
        atomicAdd(&Asu[(ed1 & 63) * 65 + (es1 & 63)], 1u);
        atomicAdd(&Asu[(ed2 & 63) * 65 + (es2 & 63)], 1u);
        atomicAdd(&Asu[(ed3 & 63) * 65 + (es3 & 63)], 1u);
    } else {
        for (int k = tid; k < epg; k += 512) {
            int e = g + k * G;
            atomicAdd(&Asu[(ei[E + e] & 63) * 65 + (ei[e] & 63)], 1u);
        }
    }
    __syncthreads();

    // counts -> float in place (exact for small ints)
    for (int idx = tid; idx < 64 * 65; idx += 512)
        Asf[idx] = (float)Asu[idx];
    __syncthreads();

    // agg = A @ h2 : thread owns (n, n+32) x 4 channels
    int c4 = (tid & 15) * 4;
    int n0 = tid >> 4;  // 0..31
#pragma unroll
    for (int i = 0; i < 2; ++i) {
        int n = n0 + 32 * i;
        float4 a4 = {0.f, 0.f, 0.f, 0.f};
#pragma unroll 4
        for (int s = 0; s < 64; ++s) {
            float a = Asf[n * 65 + s];
            float4 hv = *(const float4*)&h2s[s * CST + c4];
            a4.x += a * hv.x; a4.y += a * hv.y;
            a4.z += a * hv.z; a4.w += a * hv.w;
        }
        *(float4*)&aggs[n * CST + c4] = a4;
    }
    __syncthreads();

    // part 2: wave w owns j in [16w, 16w+16); lane = node.
    int lane = tid & 63;
    int w = __builtin_amdgcn_readfirstlane(tid >> 6);  // 0..7, uniform
    const float* __restrict__ rwb = rel_w + (size_t)(w * 16) * DLAT;
    const float* __restrict__ owb = root_w + (size_t)(w * 16) * DLAT;

    float acc[16];
#pragma unroll
    for (int jq = 0; jq < 16; ++jq) acc[jq] = 0.f;

#pragma unroll 4
    for (int m = 0; m < DLAT / 4; ++m) {
        float4 av = *(const float4*)&aggs[lane * CST + 4 * m];
        float4 hv = *(const float4*)&h2s[lane * CST + 4 * m];
#pragma unroll
        for (int jq = 0; jq < 16; ++jq) {
            const float* rp = rwb + jq * DLAT + 4 * m;  // uniform -> s_load
            const float* op = owb + jq * DLAT + 4 * m;
            acc[jq] += av.x * rp[0] + av.y * rp[1] + av.z * rp[2] + av.w * rp[3]
                     + hv.x * op[0] + hv.y * op[1] + hv.z * op[2] + hv.w * op[3];
        }
    }

#pragma unroll
    for (int jq = 0; jq < 16; ++jq) {
        int j = w * 16 + jq;
        float outv = acc[jq] + rel_b[j];
        float sq = outv * outv;
#pragma unroll
        for (int off = 32; off; off >>= 1) {
            outv += __shfl_xor(outv, off);
            sq += __shfl_xor(sq, off);
        }
        if (lane == 0) {
            Sg[g * DHID + j] = outv;
            Qg[g * DHID + j] = sq;
        }
    }
}

// ---------------------------------------------------------------------------
// Phase D: BN stats per channel -> a[j], b[j] (scale/shift)
// ---------------------------------------------------------------------------
__global__ __launch_bounds__(256) void phaseD2(const float* __restrict__ Sg,
                                               const float* __restrict__ Qg,
                                               const float* __restrict__ gamma,
                                               const float* __restrict__ beta,
                                               float* __restrict__ ab,
                                               int G, int N) {
    int j = blockIdx.x;
    int t = threadIdx.x;
    float s = 0.f, q = 0.f;
    for (int g = t; g < G; g += 256) {
        s += Sg[g * DHID + j];
        q += Qg[g * DHID + j];
    }
#pragma unroll
    for (int off = 32; off; off >>= 1) {
        s += __shfl_xor(s, off);
        q += __shfl_xor(q, off);
    }
    __shared__ float rs[4], rq[4];
    int wv = t >> 6;
    if ((t & 63) == 0) { rs[wv] = s; rq[wv] = q; }
    __syncthreads();
    if (t == 0) {
        s = rs[0] + rs[1] + rs[2] + rs[3];
        q = rq[0] + rq[1] + rq[2] + rq[3];
        float inv_n = 1.f / (float)N;
        float mean = s * inv_n;
        float var = q * inv_n - mean * mean;
        float a = rsqrtf(var + 1e-5f) * gamma[j];
        float b = beta[j] - mean * a;
        ab[j] = a;
        ab[DHID + j] = b;
    }
}

// ---------------------------------------------------------------------------
// Phase E: pooled = (a^2 Q + 2ab S)/64 + b^2 ; log(clamp) ; fc2 ; sigmoid
// ---------------------------------------------------------------------------
__global__ __launch_bounds__(128) void phaseE(const float* __restrict__ Sg,
                                              const float* __restrict__ Qg,
                                              const float* __restrict__ ab,
                                              const float* __restrict__ fc2_w,
                                              const float* __restrict__ fc2_b,
                                              float* __restrict__ y) {
    int g = blockIdx.x;
    int j = threadIdx.x;
    __shared__ float ps[DHID];
    float a = ab[j], b = ab[DHID + j];
    float S = Sg[g * DHID + j], Q = Qg[g * DHID + j];
    float pooled = (a * a * Q + 2.f * a * b * S) * (1.f / 64.f) + b * b;
    pooled = fmaxf(pooled, 1e-6f);
    ps[j] = logf(pooled);
    __syncthreads();
    if (j < 3) {
        float acc = fc2_b[j];
        for (int c = 0; c < DHID; ++c) acc += ps[c] * fc2_w[j * DHID + c];
        y[g * 3 + j] = 1.f / (1.f + expf(-acc));
    }
}

// ---------------------------------------------------------------------------
extern "C" void kernel_launch(void* const* d_in, const int* in_sizes, int n_in,
                              void* d_out, int out_size, void* d_ws, size_t ws_size,
                              hipStream_t stream) {
    const float* x      = (const float*)d_in[0];
    const int*   ei     = (const int*)d_in[1];
    const float* conv_w = (const float*)d_in[3];
    const float* conv_b = (const float*)d_in[4];
    const float* fc1_w  = (const float*)d_in[5];
    const float* fc1_b  = (const float*)d_in[6];
    const float* rel_w  = (const float*)d_in[7];
    const float* rel_b  = (const float*)d_in[8];
    const float* root_w = (const float*)d_in[9];
    const float* gamma  = (const float*)d_in[10];
    const float* beta   = (const float*)d_in[11];
    const float* fc2_w  = (const float*)d_in[12];
    const float* fc2_b  = (const float*)d_in[13];
    float* y = (float*)d_out;

    int N = in_sizes[2];       // 32768
    int E = in_sizes[1] / 2;   // 1048576
    int G = N / 64;            // 512

    float* h2 = (float*)d_ws;                  // N*64 f32
    float* Sg = h2 + (size_t)N * DLAT;         // G*128
    float* Qg = Sg + (size_t)G * DHID;         // G*128
    float* ab = Qg + (size_t)G * DHID;         // 2*128
    float* Wm = ab + 2 * DHID;                 // 64*100
    float* b2 = Wm + 64 * T_LEN;               // 64

    buildW<<<26, 256, 0, stream>>>(conv_w, conv_b, fc1_w, fc1_b, Wm, b2);
    phaseA3<<<N / 64, 512, 0, stream>>>(x, Wm, b2, h2);
    phaseCF<<<G, 512, 0, stream>>>(h2, ei, rel_w, rel_b, root_w, Sg, Qg, E, G);
    phaseD2<<<DHID, 256, 0, stream>>>(Sg, Qg, gamma, beta, ab, G, N);
    phaseE<<<G, DHID, 0, stream>>>(Sg, Qg, ab, fc2_w, fc2_b, y);
}

// Round 2
// 176.280 us; speedup vs baseline: 1.3815x; 1.2512x over previous
//
#include <hip/hip_runtime.h>
#include <math.h>

#define T_LEN 100
#define K_LEN 25
#define DLAT 64
#define DHID 128
#define CST 68
#define AST 68

// ---------------------------------------------------------------------------
// buildW: collapse Conv1d(1,64,25,pad=12) + Linear(100,1) into one matrix:
//   h2[n,c] = sum_i x[n,i] * W[c,i] + b2[c]
// ---------------------------------------------------------------------------
__global__ __launch_bounds__(256) void buildW(const float* __restrict__ conv_w,
                                              const float* __restrict__ conv_b,
                                              const float* __restrict__ fc1_w,
                                              const float* __restrict__ fc1_b,
                                              float* __restrict__ W,
                                              float* __restrict__ b2) {
    int idx = blockIdx.x * 256 + threadIdx.x;
    if (idx < 64 * T_LEN) {
        int c = idx / T_LEN, i = idx % T_LEN;
        int t0 = i - 12 > 0 ? i - 12 : 0;
        int t1 = i + 12 < T_LEN - 1 ? i + 12 : T_LEN - 1;
        float acc = 0.f;
        for (int t = t0; t <= t1; ++t)
            acc += fc1_w[t] * conv_w[c * K_LEN + (i - t + 12)];
        W[idx] = acc;
    } else if (idx < 64 * T_LEN + 64) {
        int c = idx - 64 * T_LEN;
        float S = 0.f;
        for (int t = 0; t < T_LEN; ++t) S += fc1_w[t];
        b2[c] = conv_b[c] * S + fc1_b[0];
    }
}

// ---------------------------------------------------------------------------
// phaseCF2: one block per graph (512 thr = 8 waves). Everything fused:
//   0. issue this graph's 2048 strided edge loads (latency hidden under 1.)
//   1. h2 (encoder) straight into LDS: wave w computes channels [8w,8w+8)
//      for node=lane via x (per-lane row) and W (uniform s_load stream)
//   2. LDS-atomic 64x64 adjacency count
//   3. agg = A @ h2 (u32 counts converted inline with v_cvt)
//   4. out = agg.rel^T + h2.root^T + rel_b; emit Sg=sum_n out, Qg=sum_n out^2
//      Part-2 tiling jb=2/mc=4: weights as 16-consecutive-float UNIFORM
//      chunks (s_load_dwordx16-mergeable, read exactly once per wave),
//      z rows in registers per chunk, acc[8] per jb.
// 3 barriers total. LDS 51 KB -> 2 blocks/CU (grid-limited), 16 waves/CU.
// ---------------------------------------------------------------------------
__global__ __launch_bounds__(512, 4) void phaseCF2(const float* __restrict__ x,
                                                   const int* __restrict__ ei,
                                                   const float* __restrict__ Wm,
                                                   const float* __restrict__ b2,
                                                   const float* __restrict__ rel_w,
                                                   const float* __restrict__ rel_b,
                                                   const float* __restrict__ root_w,
                                                   float* __restrict__ Sg,
                                                   float* __restrict__ Qg,
                                                   int E, int G) {
    __shared__ float h2s[64 * CST];
    __shared__ float aggs[64 * CST];
    __shared__ unsigned Asu[64 * AST];

    int tid = threadIdx.x;
    int bid = blockIdx.x;
    int lane = tid & 63;
    int w = __builtin_amdgcn_readfirstlane(tid >> 6);  // 0..7, uniform

    // bijective XCD swizzle (m204): graphs sharing edge cachelines land on
    // the same XCD so the stride-G edge reads are L2 hits.
    int q = G >> 3, r = G & 7;
    int xc = bid & 7, o = bid >> 3;
    int g = (xc < r ? xc * (q + 1) : r * (q + 1) + (xc - r) * q) + o;

    int epg = E / G;
    bool fast = (epg == 2048);

    // 0. issue strided edge loads EARLY; vmcnt FIFO means they drain before
    // the h2s stores do, i.e. fully hidden under phase 1.
    int es0 = 0, es1 = 0, es2 = 0, es3 = 0;
    int ed0 = 0, ed1 = 0, ed2 = 0, ed3 = 0;
    if (fast) {
        int e0 = g + tid * G;
        int st = 512 * G;
        es0 = ei[e0];            ed0 = ei[E + e0];
        es1 = ei[e0 + st];       ed1 = ei[E + e0 + st];
        es2 = ei[e0 + 2 * st];   ed2 = ei[E + e0 + 2 * st];
        es3 = ei[e0 + 3 * st];   ed3 = ei[E + e0 + 3 * st];
    }

    // zero adjacency counters
    for (int idx = tid; idx < 64 * AST; idx += 512) Asu[idx] = 0u;

    // 1. encoder: h2s[lane][8w..8w+8)
    {
        const float4* __restrict__ xp =
            (const float4*)(x + (size_t)(g * 64 + lane) * T_LEN);
        const float* __restrict__ Wb = Wm + w * 8 * T_LEN;  // uniform
        float acc[8];
#pragma unroll
        for (int c = 0; c < 8; ++c) acc[c] = 0.f;
#pragma unroll
        for (int tq = 0; tq < T_LEN / 4; ++tq) {
            float4 xv = xp[tq];
#pragma unroll
            for (int c = 0; c < 8; ++c) {
                const float* wr = Wb + c * T_LEN + tq * 4;  // uniform -> s_load
                acc[c] += xv.x * wr[0] + xv.y * wr[1] + xv.z * wr[2] + xv.w * wr[3];
            }
        }
        float4 o0, o1;
        o0.x = acc[0] + b2[w * 8 + 0];
        o0.y = acc[1] + b2[w * 8 + 1];
        o0.z = acc[2] + b2[w * 8 + 2];
        o0.w = acc[3] + b2[w * 8 + 3];
        o1.x = acc[4] + b2[w * 8 + 4];
        o1.y = acc[5] + b2[w * 8 + 5];
        o1.z = acc[6] + b2[w * 8 + 6];
        o1.w = acc[7] + b2[w * 8 + 7];
        *(float4*)&h2s[lane * CST + w * 8] = o0;
        *(float4*)&h2s[lane * CST + w * 8 + 4] = o1;
    }
    __syncthreads();

    // 2. edge counting via LDS atomics
    if (fast) {
        atomicAdd(&Asu[(ed0 & 63) * AST + (es0 & 63)], 1u);
        atomicAdd(&Asu[(ed1 & 63) * AST + (es1 & 63)], 1u);
        atomicAdd(&Asu[(ed2 & 63) * AST + (es2 & 63)], 1u);
        atomicAdd(&Asu[(ed3 & 63) * AST + (es3 & 63)], 1u);
    } else {
        for (int k = tid; k < epg; k += 512) {
            int e = g + k * G;
            atomicAdd(&Asu[(ei[E + e] & 63) * AST + (ei[e] & 63)], 1u);
        }
    }
    __syncthreads();

    // 3. agg = A @ h2 (convert counts inline). thread owns (n, n+32) x 4 ch.
    {
        int c4 = (tid & 15) * 4;
        int n0 = tid >> 4;  // 0..31
#pragma unroll
        for (int i = 0; i < 2; ++i) {
            int n = n0 + 32 * i;
            float4 a4 = {0.f, 0.f, 0.f, 0.f};
#pragma unroll 4
            for (int s4 = 0; s4 < 16; ++s4) {
                uint4 au = *(const uint4*)&Asu[n * AST + 4 * s4];
                float a0 = (float)au.x, a1 = (float)au.y;
                float a2 = (float)au.z, a3 = (float)au.w;
                float4 h0 = *(const float4*)&h2s[(4 * s4 + 0) * CST + c4];
                float4 h1 = *(const float4*)&h2s[(4 * s4 + 1) * CST + c4];
                float4 h2v = *(const float4*)&h2s[(4 * s4 + 2) * CST + c4];
                float4 h3 = *(const float4*)&h2s[(4 * s4 + 3) * CST + c4];
                a4.x += a0 * h0.x + a1 * h1.x + a2 * h2v.x + a3 * h3.x;
                a4.y += a0 * h0.y + a1 * h1.y + a2 * h2v.y + a3 * h3.y;
                a4.z += a0 * h0.z + a1 * h1.z + a2 * h2v.z + a3 * h3.z;
                a4.w += a0 * h0.w + a1 * h1.w + a2 * h2v.w + a3 * h3.w;
            }
            *(float4*)&aggs[n * CST + c4] = a4;
        }
    }
    __syncthreads();

    // 4. part2: wave w owns j in [16w,16w+16), jb halves of 8, mc chunks of 16c
#pragma unroll
    for (int jb = 0; jb < 2; ++jb) {
        float acc[8];
#pragma unroll
        for (int ji = 0; ji < 8; ++ji) acc[ji] = 0.f;

#pragma unroll
        for (int mc = 0; mc < 4; ++mc) {
            float4 za[4], zh[4];
#pragma unroll
            for (int k = 0; k < 4; ++k) {
                za[k] = *(const float4*)&aggs[lane * CST + mc * 16 + 4 * k];
                zh[k] = *(const float4*)&h2s[lane * CST + mc * 16 + 4 * k];
            }
#pragma unroll
            for (int ji = 0; ji < 8; ++ji) {
                int j = w * 16 + jb * 8 + ji;  // uniform
                const float* rp = rel_w + (size_t)j * DLAT + mc * 16;  // 64B run
                const float* op = root_w + (size_t)j * DLAT + mc * 16;
                float a = acc[ji];
#pragma unroll
                for (int k = 0; k < 4; ++k) {
                    a += za[k].x * rp[4 * k + 0] + za[k].y * rp[4 * k + 1] +
                         za[k].z * rp[4 * k + 2] + za[k].w * rp[4 * k + 3];
                    a += zh[k].x * op[4 * k + 0] + zh[k].y * op[4 * k + 1] +
                         zh[k].z * op[4 * k + 2] + zh[k].w * op[4 * k + 3];
                }
                acc[ji] = a;
            }
        }

#pragma unroll
        for (int ji = 0; ji < 8; ++ji) {
            int j = w * 16 + jb * 8 + ji;
            float outv = acc[ji] + rel_b[j];
            float sq = outv * outv;
#pragma unroll
            for (int off = 32; off; off >>= 1) {
                outv += __shfl_xor(outv, off);
                sq += __shfl_xor(sq, off);
            }
            if (lane == 0) {
                Sg[g * DHID + j] = outv;
                Qg[g * DHID + j] = sq;
            }
        }
    }
}

// ---------------------------------------------------------------------------
// Phase D: BN stats per channel -> a[j], b[j] (scale/shift)
// ---------------------------------------------------------------------------
__global__ __launch_bounds__(256) void phaseD2(const float* __restrict__ Sg,
                                               const float* __restrict__ Qg,
                                               const float* __restrict__ gamma,
                                               const float* __restrict__ beta,
                                               float* __restrict__ ab,
                                               int G, int N) {
    int j = blockIdx.x;
    int t = threadIdx.x;
    float s = 0.f, q = 0.f;
    for (int g = t; g < G; g += 256) {
        s += Sg[g * DHID + j];
        q += Qg[g * DHID + j];
    }
#pragma unroll
    for (int off = 32; off; off >>= 1) {
        s += __shfl_xor(s, off);
        q += __shfl_xor(q, off);
    }
    __shared__ float rs[4], rq[4];
    int wv = t >> 6;
    if ((t & 63) == 0) { rs[wv] = s; rq[wv] = q; }
    __syncthreads();
    if (t == 0) {
        s = rs[0] + rs[1] + rs[2] + rs[3];
        q = rq[0] + rq[1] + rq[2] + rq[3];
        float inv_n = 1.f / (float)N;
        float mean = s * inv_n;
        float var = q * inv_n - mean * mean;
        float a = rsqrtf(var + 1e-5f) * gamma[j];
        float b = beta[j] - mean * a;
        ab[j] = a;
        ab[DHID + j] = b;
    }
}

// ---------------------------------------------------------------------------
// Phase E: pooled = (a^2 Q + 2ab S)/64 + b^2 ; log(clamp) ; fc2 ; sigmoid
// ---------------------------------------------------------------------------
__global__ __launch_bounds__(128) void phaseE(const float* __restrict__ Sg,
                                              const float* __restrict__ Qg,
                                              const float* __restrict__ ab,
                                              const float* __restrict__ fc2_w,
                                              const float* __restrict__ fc2_b,
                                              float* __restrict__ y) {
    int g = blockIdx.x;
    int j = threadIdx.x;
    __shared__ float ps[DHID];
    float a = ab[j], b = ab[DHID + j];
    float S = Sg[g * DHID + j], Q = Qg[g * DHID + j];
    float pooled = (a * a * Q + 2.f * a * b * S) * (1.f / 64.f) + b * b;
    pooled = fmaxf(pooled, 1e-6f);
    ps[j] = logf(pooled);
    __syncthreads();
    if (j < 3) {
        float acc = fc2_b[j];
        for (int c = 0; c < DHID; ++c) acc += ps[c] * fc2_w[j * DHID + c];
        y[g * 3 + j] = 1.f / (1.f + expf(-acc));
    }
}

// ---------------------------------------------------------------------------
extern "C" void kernel_launch(void* const* d_in, const int* in_sizes, int n_in,
                              void* d_out, int out_size, void* d_ws, size_t ws_size,
                              hipStream_t stream) {
    const float* x      = (const float*)d_in[0];
    const int*   ei     = (const int*)d_in[1];
    const float* conv_w = (const float*)d_in[3];
    const float* conv_b = (const float*)d_in[4];
    const float* fc1_w  = (const float*)d_in[5];
    const float* fc1_b  = (const float*)d_in[6];
    const float* rel_w  = (const float*)d_in[7];
    const float* rel_b  = (const float*)d_in[8];
    const float* root_w = (const float*)d_in[9];
    const float* gamma  = (const float*)d_in[10];
    const float* beta   = (const float*)d_in[11];
    const float* fc2_w  = (const float*)d_in[12];
    const float* fc2_b  = (const float*)d_in[13];
    float* y = (float*)d_out;

    int N = in_sizes[2];       // 32768
    int E = in_sizes[1] / 2;   // 1048576
    int G = N / 64;            // 512

    float* Sg = (float*)d_ws;                  // G*128
    float* Qg = Sg + (size_t)G * DHID;         // G*128
    float* ab = Qg + (size_t)G * DHID;         // 2*128
    float* Wm = ab + 2 * DHID;                 // 64*100
    float* b2 = Wm + 64 * T_LEN;               // 64

    buildW<<<26, 256, 0, stream>>>(conv_w, conv_b, fc1_w, fc1_b, Wm, b2);
    phaseCF2<<<G, 512, 0, stream>>>(x, ei, Wm, b2, rel_w, rel_b, root_w,
                                    Sg, Qg, E, G);
    phaseD2<<<DHID, 256, 0, stream>>>(Sg, Qg, gamma, beta, ab, G, N);
    phaseE<<<G, DHID, 0, stream>>>(Sg, Qg, ab, fc2_w, fc2_b, y);
}